// Round 1
// baseline (123.501 us; speedup 1.0000x reference)
//
#include <hip/hip_runtime.h>

// Sinkhorn fixed-point for fermionic canonical ensembles.
// B=2048 systems, P=64 orbitals, N_PART=32, n_iters from d_in[2].
//
// R13 = R12 restructured to ONE system per wave (2048 waves -> 2 waves/SIMD)
// to attack the latency-bound regime (R12: VALUBusy 58%, Occ 9.9%, 1
// wave/SIMD, ~3100 stall cyc/iter that intra-wave fusion could not fill --
// R11->R12 was neutral). Lane layout: 64 lanes = 64 orbitals for all
// per-orbital phases; for C_k the lanes split as k = l32+1 with lanes 0-31
// running numpy accumulators 0-3 and lanes 32-63 accumulators 4-7; the
// cross-lane combine tLo + tHi reproduces numpy's tree
// ((a0+a1)+(a2+a3)) + ((a4+a5)+(a6+a7)) bit-exactly. Every scalar op
// sequence (exp/log/rcp/sweep/aux/update/reductions) is value-identical to
// R12 -> result must be bit-identical. Per-wave issue ~0.6x (32 vector
// exps instead of 64, single-system sweep/aux/update), and two co-resident
// waves per SIMD hide each other's dependency stalls.
// Everything else identical to R12: per-system numpy op order,
// contract(off), Cody-Waite exp/log, ~1ulp rcp_nr, Er preload + volatile
// pins, barrier-bracketed LDS staging (64-thread block => barriers don't
// couple the two waves on a SIMD; they drift into antiphase).
// CANARY: absmax must be exactly 0.015625.

#pragma clang fp contract(off)

#define NPART 32
#define PORB  64

#define L2E_HI 1.44269502162933349609375f
#define L2E_LO 1.9259629911266175e-08f
#define LN2_HI 0.69314718246459960938f
#define LN2_LO -1.9046542121259175e-09f
#define LN2F   0.6931471805599453f

__device__ __forceinline__ float readlane_f(float v, int srclane) {
    return __int_as_float(__builtin_amdgcn_readlane(__float_as_int(v), srclane));
}

// reciprocal: v_rcp_f32 + one Newton step => ~0.5-1 ulp
__device__ __forceinline__ float rcp_nr(float d) {
    float r = __builtin_amdgcn_rcpf(d);
    float e = fmaf(-d, r, 1.0f);
    return fmaf(r, e, r);
}

// e^arg with Cody-Waite correction (<=1.5 ulp), arg pre-rounded like numpy
__device__ __forceinline__ float exp_acc(float arg) {
    float p    = arg * L2E_HI;
    float perr = fmaf(arg, L2E_HI, -p);
    float c    = fmaf(arg, L2E_LO, perr);
    float e0   = __builtin_amdgcn_exp2f(p);
    return fmaf(e0, c * LN2F, e0);
}

// ln(x) = log2(x)*ln2 with split constant (~1.5 ulp)
__device__ __forceinline__ float ln_acc(float x) {
    float l2 = __log2f(x);
    float p  = l2 * LN2_HI;
    float e  = fmaf(l2, LN2_HI, -p);
    return p + fmaf(l2, LN2_LO, e);
}

// numpy pairwise_sum over one system's 64 orbitals, 1 orbital per lane.
// Lane j (j<8) builds accumulator r[j] = n_j + n_{j+8} + ... + n_{j+56}
// (sequential, numpy order), then the readlane tree combines
// ((r0+r1)+(r2+r3)) + ((r4+r5)+(r6+r7)) -- identical values/order to R12's
// red_np (which built the same 8 sequential sums from its v0/v1 split).
__device__ __forceinline__ float red64(float v, int lane) {
    float c = v;
    c = c + __shfl(v, (lane + 8)  & 63);
    c = c + __shfl(v, (lane + 16) & 63);
    c = c + __shfl(v, (lane + 24) & 63);
    c = c + __shfl(v, (lane + 32) & 63);
    c = c + __shfl(v, (lane + 40) & 63);
    c = c + __shfl(v, (lane + 48) & 63);
    c = c + __shfl(v, (lane + 56) & 63);
    return ((readlane_f(c, 0) + readlane_f(c, 1)) +
            (readlane_f(c, 2) + readlane_f(c, 3))) +
           ((readlane_f(c, 4) + readlane_f(c, 5)) +
            (readlane_f(c, 6) + readlane_f(c, 7)));
}

__global__ __launch_bounds__(PORB)
__attribute__((amdgpu_waves_per_eu(2)))
void sinkhorn_kernel(
    const float* __restrict__ n_in,
    const float* __restrict__ beta_ptr,
    const int*   __restrict__ iters_ptr,
    float*       __restrict__ out)
{
    const int b    = blockIdx.x;                // system index
    const int lane = threadIdx.x;               // orbital index
    const int l32  = lane & 31;
    const int h    = lane >> 5;                 // accumulator half for C_k

    const float beta    = beta_ptr[0];
    const int   n_iters = iters_ptr[0];
    const float nb      = -beta;
    const float inv_beta = rcp_nr(beta);

    __shared__ __align__(16) float t_sh[PORB];  // eps staging, 1 system

    const int sysbase = b * PORB;
    const float n0 = n_in[sysbase + lane];      // this lane's orbital

    // ---- setup: nn, snn, ratio, eps0 (per-orbital values == R12) ----
    const float srt  = red64(n0, lane);
    const float isrt = rcp_nr(srt);
    const float nn   = (n0 * isrt) * (float)NPART;
    const float snn  = red64(nn, lane);
    const float inv_snn = rcp_nr(snn);
    const float ratio   = nn * rcp_nr(1.0f - nn);
    float eps = (-ln_acc(ratio)) * inv_beta;

    const float kf = (float)(l32 + 1);          // this lane's k (both halves)
    const float mk = nb * kf;

    for (int it = 0; it < n_iters; ++it) {
        // ---- stage eps (barrier-bracketed; single-wave block) ----
        __syncthreads();
        t_sh[lane] = eps;
        __syncthreads();

        // ---- C_k: lane (k-1, half h) builds numpy accumulators 4h..4h+3.
        // Lo lanes read eps[8i..8i+3], hi lanes eps[8i+4..8i+7]; uniform
        // address per half => broadcast, conflict-free. Accumulation order
        // per accumulator and the final combine tree are identical to R12.
        const float4* t4 = reinterpret_cast<const float4*>(t_sh);
        float a0, a1, a2, a3;
        #pragma unroll
        for (int i = 0; i < 8; ++i) {
            const float4 va = t4[2 * i + h];
            const float e0 = exp_acc(mk * va.x);
            const float e1 = exp_acc(mk * va.y);
            const float e2 = exp_acc(mk * va.z);
            const float e3 = exp_acc(mk * va.w);
            if (i == 0) { a0 = e0; a1 = e1; a2 = e2; a3 = e3; }
            else        { a0 += e0; a1 += e1; a2 += e2; a3 += e3; }
        }
        const float t = (a0 + a1) + (a2 + a3);  // tLo (h=0) / tHi (h=1)
        // C[k] = tLo + tHi == ((a0+a1)+(a2+a3)) + ((a4+a5)+(a6+a7))
        const float Cfull = __shfl(t, l32) + __shfl(t, l32 + 32);
        // lanes k-1 and k-1+32 both hold C[k]

        const float c1v = readlane_f(Cfull, 0);  // C[1]

        // E[i] = C[i+1]/C[i] (l32==0 junk, never consumed by live lanes)
        const float prevC = __shfl(Cfull, (l32 - 1) & 31);
        const float E     = Cfull * rcp_nr(prevC);

        // ---- preload + pin the 31 E-gathers (R8 win) ----
        float Er[NPART];
        #pragma unroll
        for (int s = 1; s < NPART; ++s) {
            Er[s] = __shfl(E, (l32 + 1 - s) & 31);
            asm volatile("" : "+v"(Er[s]));      // schedule pin only
        }

        // ---- aux input, hoisted (depends only on eps) ----
        const float x = exp_acc(nb * eps);

        // ---- fused sweep + aux (R12 structure, single system): lane-
        // pipelined Q recursion; aux step s executes as soon as invQ[s]
        // exists. Same ops/order/rounding as R12 per orbital.
        const float invQ0 = rcp_nr(c1v);
        float prev;
        {
            const float a = (x * invQ0) * 1.0f;  // prev = 1.0 initially
            prev = 1.0f - a;
        }
        float y30 = 0.0f;
        float invQprev = invQ0;                  // invQ[s-1] carry
        float p = 1.0f;
        #pragma unroll
        for (int s = 1; s < NPART; ++s) {
            const float d = Er[s] * invQprev;
            const float m = d * p;
            p = 1.0f - m;
            const float psv = readlane_f(p, s);
            const float invQs = (float)(s + 1) * rcp_nr(c1v * psv);
            // aux step s (inline g = x*invQ[s]; same rounding as R12)
            const float a = (x * invQs) * prev;
            prev = 1.0f - a;
            if (s == NPART - 2) y30 = prev;
            invQprev = invQs;
        }
        const float invQ31 = invQprev;           // invQ[NPART-1]
        const float Qp1 = prev;
        const float Qp0 = y30 * invQ31;

        // ---- update + normalize (identical per-orbital ops to R12) ----
        const float q  = (ratio * Qp1) * rcp_nr(Qp0);
        const float en = (-ln_acc(q)) * inv_beta;

        const float W = red64(nn * en, lane);
        const float corr = W * inv_snn;
        eps = en - corr;
    }

    out[sysbase + lane] = eps;
}

extern "C" void kernel_launch(void* const* d_in, const int* in_sizes, int n_in,
                              void* d_out, int out_size, void* d_ws, size_t ws_size,
                              hipStream_t stream) {
    const float* n_ptr    = (const float*)d_in[0];
    const float* beta_ptr = (const float*)d_in[1];
    const int*   it_ptr   = (const int*)d_in[2];
    float*       out      = (float*)d_out;

    const int B = in_sizes[0] / PORB;   // 2048 systems, one per wave
    sinkhorn_kernel<<<B, PORB, 0, stream>>>(n_ptr, beta_ptr, it_ptr, out);
}

// Round 2
// 117.039 us; speedup vs baseline: 1.0552x; 1.0552x over previous
//
#include <hip/hip_runtime.h>

// Sinkhorn fixed-point for fermionic canonical ensembles.
// B=2048 systems, P=64 orbitals, N_PART=32, n_iters from d_in[2].
//
// R14 = R13 (1 system/wave, 2048 waves -> 2 waves/SIMD) + PHASE ROTATION.
// R13 post-mortem: occupancy doubled (9.9->18.9%) but VALUBusy stayed at
// 58% (same as R12's single-wave value) and dur regressed 60.9->74.9us.
// Diagnosis: the two co-resident waves run identical code launched
// simultaneously -> they enter the latency-bound 31-step sweep at the same
// time; their stall windows are correlated, so 42% of cycles NEITHER wave
// can issue. Fix: half the blocks (phase bit covers both plausible
// same-SIMD pairing models: offset-1024 global round-robin and offset-4
// CU-fill) run the iteration loop ROTATED: prologue {P0;P1}, body
// {P2;P0;P1}, tail {P2}. Per-system op sequence is (P0 P1 P2)^n either
// way -> bit-identical results; only the source loop structure changes.
// In steady state rotated waves run ~0.7 iter ahead, so a wave's sweep
// stalls overlap its SIMD partner's issue-dense C_k exp block.
// Everything else identical to R13: per-system numpy op order,
// contract(off), Cody-Waite exp/log, ~1ulp rcp_nr, Er preload + volatile
// pins, barrier-bracketed LDS staging (single-wave block: barriers do not
// couple waves across blocks).
// CANARY: absmax must be exactly 0.015625.

#pragma clang fp contract(off)

#define NPART 32
#define PORB  64

#define L2E_HI 1.44269502162933349609375f
#define L2E_LO 1.9259629911266175e-08f
#define LN2_HI 0.69314718246459960938f
#define LN2_LO -1.9046542121259175e-09f
#define LN2F   0.6931471805599453f

__device__ __forceinline__ float readlane_f(float v, int srclane) {
    return __int_as_float(__builtin_amdgcn_readlane(__float_as_int(v), srclane));
}

// reciprocal: v_rcp_f32 + one Newton step => ~0.5-1 ulp
__device__ __forceinline__ float rcp_nr(float d) {
    float r = __builtin_amdgcn_rcpf(d);
    float e = fmaf(-d, r, 1.0f);
    return fmaf(r, e, r);
}

// e^arg with Cody-Waite correction (<=1.5 ulp), arg pre-rounded like numpy
__device__ __forceinline__ float exp_acc(float arg) {
    float p    = arg * L2E_HI;
    float perr = fmaf(arg, L2E_HI, -p);
    float c    = fmaf(arg, L2E_LO, perr);
    float e0   = __builtin_amdgcn_exp2f(p);
    return fmaf(e0, c * LN2F, e0);
}

// ln(x) = log2(x)*ln2 with split constant (~1.5 ulp)
__device__ __forceinline__ float ln_acc(float x) {
    float l2 = __log2f(x);
    float p  = l2 * LN2_HI;
    float e  = fmaf(l2, LN2_HI, -p);
    return p + fmaf(l2, LN2_LO, e);
}

// numpy pairwise_sum over one system's 64 orbitals, 1 orbital per lane.
// Identical values/order to R13's red64.
__device__ __forceinline__ float red64(float v, int lane) {
    float c = v;
    c = c + __shfl(v, (lane + 8)  & 63);
    c = c + __shfl(v, (lane + 16) & 63);
    c = c + __shfl(v, (lane + 24) & 63);
    c = c + __shfl(v, (lane + 32) & 63);
    c = c + __shfl(v, (lane + 40) & 63);
    c = c + __shfl(v, (lane + 48) & 63);
    c = c + __shfl(v, (lane + 56) & 63);
    return ((readlane_f(c, 0) + readlane_f(c, 1)) +
            (readlane_f(c, 2) + readlane_f(c, 3))) +
           ((readlane_f(c, 4) + readlane_f(c, 5)) +
            (readlane_f(c, 6) + readlane_f(c, 7)));
}

__global__ __launch_bounds__(PORB)
__attribute__((amdgpu_waves_per_eu(2)))
void sinkhorn_kernel(
    const float* __restrict__ n_in,
    const float* __restrict__ beta_ptr,
    const int*   __restrict__ iters_ptr,
    float*       __restrict__ out)
{
    const int b    = blockIdx.x;                // system index
    const int lane = threadIdx.x;               // orbital index
    const int l32  = lane & 31;
    const int h    = lane >> 5;                 // accumulator half for C_k

    const float beta    = beta_ptr[0];
    const int   n_iters = iters_ptr[0];
    const float nb      = -beta;
    const float inv_beta = rcp_nr(beta);

    __shared__ __align__(16) float t_sh[PORB];  // eps staging, 1 system

    const int sysbase = b * PORB;
    const float n0 = n_in[sysbase + lane];      // this lane's orbital

    // ---- setup: nn, snn, ratio, eps0 (per-orbital values == R13) ----
    const float srt  = red64(n0, lane);
    const float isrt = rcp_nr(srt);
    const float nn   = (n0 * isrt) * (float)NPART;
    const float snn  = red64(nn, lane);
    const float inv_snn = rcp_nr(snn);
    const float ratio   = nn * rcp_nr(1.0f - nn);
    float eps = (-ln_acc(ratio)) * inv_beta;

    const float kf = (float)(l32 + 1);          // this lane's k (both halves)
    const float mk = nb * kf;

    // ---- cross-phase iteration state ----
    float x, c1v;                               // P0 -> P1
    float Er[NPART];                            // P0 -> P1 (E gathers)
    float Qp0, Qp1;                             // P1 -> P2

    // ======== PHASE A = P0 (stage, C_k, E, Er, x) + P1 (sweep+aux) ========
    auto PHASE_A = [&]() {
        // ---- stage eps (barrier-bracketed; single-wave block) ----
        __syncthreads();
        t_sh[lane] = eps;
        __syncthreads();

        // ---- C_k: lane (k-1, half h) builds numpy accumulators 4h..4h+3.
        const float4* t4 = reinterpret_cast<const float4*>(t_sh);
        float a0, a1, a2, a3;
        #pragma unroll
        for (int i = 0; i < 8; ++i) {
            const float4 va = t4[2 * i + h];
            const float e0 = exp_acc(mk * va.x);
            const float e1 = exp_acc(mk * va.y);
            const float e2 = exp_acc(mk * va.z);
            const float e3 = exp_acc(mk * va.w);
            if (i == 0) { a0 = e0; a1 = e1; a2 = e2; a3 = e3; }
            else        { a0 += e0; a1 += e1; a2 += e2; a3 += e3; }
        }
        const float t = (a0 + a1) + (a2 + a3);  // tLo (h=0) / tHi (h=1)
        // C[k] = tLo + tHi == ((a0+a1)+(a2+a3)) + ((a4+a5)+(a6+a7))
        const float Cfull = __shfl(t, l32) + __shfl(t, l32 + 32);
        // lanes k-1 and k-1+32 both hold C[k]

        c1v = readlane_f(Cfull, 0);             // C[1]

        // E[i] = C[i+1]/C[i] (l32==0 junk, never consumed by live lanes)
        const float prevC = __shfl(Cfull, (l32 - 1) & 31);
        const float E     = Cfull * rcp_nr(prevC);

        // ---- preload + pin the 31 E-gathers (R8 win) ----
        #pragma unroll
        for (int s = 1; s < NPART; ++s) {
            Er[s] = __shfl(E, (l32 + 1 - s) & 31);
            asm volatile("" : "+v"(Er[s]));      // schedule pin only
        }

        // ---- aux input, hoisted (depends only on eps) ----
        x = exp_acc(nb * eps);

        // ---- fused sweep + aux (identical ops/order/rounding to R13) ----
        const float invQ0 = rcp_nr(c1v);
        float prev;
        {
            const float a = (x * invQ0) * 1.0f;  // prev = 1.0 initially
            prev = 1.0f - a;
        }
        float y30 = 0.0f;
        float invQprev = invQ0;                  // invQ[s-1] carry
        float p = 1.0f;
        #pragma unroll
        for (int s = 1; s < NPART; ++s) {
            const float d = Er[s] * invQprev;
            const float m = d * p;
            p = 1.0f - m;
            const float psv = readlane_f(p, s);
            const float invQs = (float)(s + 1) * rcp_nr(c1v * psv);
            // aux step s (inline g = x*invQ[s]; same rounding as R13)
            const float a = (x * invQs) * prev;
            prev = 1.0f - a;
            if (s == NPART - 2) y30 = prev;
            invQprev = invQs;
        }
        const float invQ31 = invQprev;           // invQ[NPART-1]
        Qp1 = prev;
        Qp0 = y30 * invQ31;
    };

    // ======== PHASE B = P2 (update + normalize) ========
    auto PHASE_B = [&]() {
        const float q  = (ratio * Qp1) * rcp_nr(Qp0);
        const float en = (-ln_acc(q)) * inv_beta;

        const float W = red64(nn * en, lane);
        const float corr = W * inv_snn;
        eps = en - corr;
    };

    // Phase bit: covers offset-1024 (global/XCD round-robin) and offset-4
    // (CU-sequential fill) same-SIMD pairing models.
    const int rot = ((b >> 10) ^ (b >> 2)) & 1;

    if (rot && n_iters > 0) {
        // rotated: A; (B;A)^(n-1); B  ==  (A;B)^n, just loop-rotated
        PHASE_A();
        for (int it = 1; it < n_iters; ++it) { PHASE_B(); PHASE_A(); }
        PHASE_B();
    } else if (!rot) {
        for (int it = 0; it < n_iters; ++it) { PHASE_A(); PHASE_B(); }
    }

    out[sysbase + lane] = eps;
}

extern "C" void kernel_launch(void* const* d_in, const int* in_sizes, int n_in,
                              void* d_out, int out_size, void* d_ws, size_t ws_size,
                              hipStream_t stream) {
    const float* n_ptr    = (const float*)d_in[0];
    const float* beta_ptr = (const float*)d_in[1];
    const int*   it_ptr   = (const int*)d_in[2];
    float*       out      = (float*)d_out;

    const int B = in_sizes[0] / PORB;   // 2048 systems, one per wave
    sinkhorn_kernel<<<B, PORB, 0, stream>>>(n_ptr, beta_ptr, it_ptr, out);
}